// Round 1
// baseline (386.214 us; speedup 1.0000x reference)
//
#include <hip/hip_runtime.h>

#define EPSF 1e-5f

constexpr int B_ = 2, N_ = 16384, K_ = 32, C_ = 64, G_ = 10;
constexpr int PTS_PER_BLOCK = 16;
constexpr int NBLOCK = (B_ * N_) / PTS_PER_BLOCK; // 2048

__global__ __launch_bounds__(256, 3) void bridgenet_kernel(
    const float* __restrict__ points,
    const float* __restrict__ features,
    const int*   __restrict__ gidx,
    const float* __restrict__ Wpos,
    const float* __restrict__ bpos,
    const float* __restrict__ bn1g, const float* __restrict__ bn1b,
    const float* __restrict__ bn1m, const float* __restrict__ bn1v,
    const float* __restrict__ Wgcm,
    const float* __restrict__ bgcm,
    const float* __restrict__ bn2g, const float* __restrict__ bn2b,
    const float* __restrict__ bn2m, const float* __restrict__ bn2v,
    const float* __restrict__ Watt,
    const float* __restrict__ batt,
    const float* __restrict__ Wout,
    const float* __restrict__ bout,
    const float* __restrict__ lng, const float* __restrict__ lnb,
    float* __restrict__ out)
{
    __shared__ float Wt_gcm[64 * 64];  // [c][d] = Wgcm[d][c]
    __shared__ float Wo_t[64 * 64];    // [c][o] = Wout[o][c]
    __shared__ float geo[32 * 10];
    __shared__ int   idxK[32];
    __shared__ float hbuf[32 * 64];    // [k][c]
    __shared__ float redbuf[8 * 64];   // score partials [grp][d]
    __shared__ float maxbuf[8 * 64];   // max partials  [grp][d]
    __shared__ float resbuf[64];
    __shared__ float ybuf[4 * 64];

    const int t = threadIdx.x;

    // ---- one-time per-block: transpose weights into LDS ----
    for (int i = t; i < 64 * 64; i += 256) {
        int d = i >> 6, c = i & 63;
        Wt_gcm[c * 64 + d] = Wgcm[i];   // Wgcm row-major (d,c)
        Wo_t[c * 64 + d]   = Wout[i];   // Wout row-major (o,c)
    }

    // ---- per-thread folded params (constant across points) ----
    const int c_lane = t & 63;          // channel for phases 2/5/6
    const int kq = t >> 6;              // wave id 0..3
    float rp[10];
    #pragma unroll
    for (int g = 0; g < 10; ++g) rp[g] = Wpos[c_lane * 10 + g];
    const float ps1 = bn1g[c_lane] * rsqrtf(bn1v[c_lane] + EPSF);
    const float pb1 = ps1 * (bpos[c_lane] - bn1m[c_lane]) + bn1b[c_lane];

    const int d2 = (t & 31) * 2;        // phase-3 output channels d2, d2+1
    const int kb = (t >> 5) * 4;        // phase-3 k-range kb..kb+3
    const float ps2a = bn2g[d2]     * rsqrtf(bn2v[d2]     + EPSF);
    const float ps2b = bn2g[d2 + 1] * rsqrtf(bn2v[d2 + 1] + EPSF);
    const float pb2a = ps2a * (bgcm[d2]     - bn2m[d2])     + bn2b[d2];
    const float pb2b = ps2b * (bgcm[d2 + 1] - bn2m[d2 + 1]) + bn2b[d2 + 1];
    float pwat[4];
    #pragma unroll
    for (int i = 0; i < 4; ++i) pwat[i] = Watt[kb + i];
    const float battv = batt[0];
    const float pbout = bout[c_lane], plng = lng[c_lane], plnb = lnb[c_lane];

    __syncthreads();

    for (int p = 0; p < PTS_PER_BLOCK; ++p) {
        const int pt = blockIdx.x * PTS_PER_BLOCK + p;  // = b*N + n
        const int b = pt >> 14;                          // / N_
        const float xi0 = points[(size_t)pt * 3 + 0];
        const float xi1 = points[(size_t)pt * 3 + 1];
        const float xi2 = points[(size_t)pt * 3 + 2];

        // ---- phase 1: gather neighbor points, build geo (t<32) ----
        if (t < 32) {
            const int k = t;
            const int id = gidx[(size_t)pt * 32 + k];
            idxK[k] = id;
            const float* pp = points + ((size_t)(b * N_ + id)) * 3;
            const float px = pp[0], py = pp[1], pz = pp[2];
            const float dx = xi0 - px, dy = xi1 - py, dz = xi2 - pz;
            const float dist = sqrtf(dx * dx + dy * dy + dz * dz);
            float* gg = &geo[k * 10];
            gg[0] = xi0; gg[1] = xi1; gg[2] = xi2;
            gg[3] = px;  gg[4] = py;  gg[5] = pz;
            gg[6] = dx;  gg[7] = dy;  gg[8] = dz; gg[9] = dist;
        }
        __syncthreads();

        // ---- phase 2: pos-MLP + bn1 + relu + feature gather → hbuf ----
        #pragma unroll
        for (int i = 0; i < 8; ++i) {
            const int k = kq * 8 + i;
            const float* gg = &geo[k * 10];
            float a = 0.f;
            #pragma unroll
            for (int g = 0; g < 10; ++g) a += gg[g] * rp[g];
            const float e = fmaxf(ps1 * a + pb1, 0.f);
            const float f = features[((size_t)(b * N_ + idxK[k])) * 64 + c_lane];
            hbuf[k * 64 + c_lane] = f + e;
        }
        __syncthreads();

        // ---- phase 3: GCM matmul (2d x 4k per thread) + bn2 + relu,
        //      fold directly into score/max partials (h2 never stored) ----
        float acc[8] = {0, 0, 0, 0, 0, 0, 0, 0};
        #pragma unroll 4
        for (int c0 = 0; c0 < 64; ++c0) {
            const float2 w = *(const float2*)&Wt_gcm[c0 * 64 + d2];
            #pragma unroll
            for (int i = 0; i < 4; ++i) {
                const float hv = hbuf[(kb + i) * 64 + c0];
                acc[2 * i]     += hv * w.x;
                acc[2 * i + 1] += hv * w.y;
            }
        }
        float spa = 0.f, spb = 0.f, ma = 0.f, mb = 0.f;  // h2>=0 so 0-init max ok
        #pragma unroll
        for (int i = 0; i < 4; ++i) {
            const float ea = fmaxf(ps2a * acc[2 * i]     + pb2a, 0.f);
            const float eb = fmaxf(ps2b * acc[2 * i + 1] + pb2b, 0.f);
            spa += ea * pwat[i]; spb += eb * pwat[i];
            ma = fmaxf(ma, ea);  mb = fmaxf(mb, eb);
        }
        {
            const int grp = t >> 5;
            redbuf[grp * 64 + d2]     = spa;
            redbuf[grp * 64 + d2 + 1] = spb;
            maxbuf[grp * 64 + d2]     = ma;
            maxbuf[grp * 64 + d2 + 1] = mb;
        }
        __syncthreads();

        // ---- phase 4: channel softmax + scaled max-pool + residual (wave 0) ----
        if (t < 64) {
            float sc = battv;
            float pm = 0.f;
            #pragma unroll
            for (int g = 0; g < 8; ++g) {
                sc += redbuf[g * 64 + t];
                pm = fmaxf(pm, maxbuf[g * 64 + t]);
            }
            float mx = sc;
            #pragma unroll
            for (int off = 32; off > 0; off >>= 1) mx = fmaxf(mx, __shfl_xor(mx, off));
            const float ex = __expf(sc - mx);
            float sm = ex;
            #pragma unroll
            for (int off = 32; off > 0; off >>= 1) sm += __shfl_xor(sm, off);
            const float sval = ex / sm;
            // softmax weight > 0 and h2 >= 0  =>  max_k(h2*s) = s * max_k h2
            resbuf[t] = sval * pm + features[(size_t)pt * 64 + t];
        }
        __syncthreads();

        // ---- phase 5: output matmul partials (all 4 waves) ----
        {
            float pp = 0.f;
            #pragma unroll
            for (int j = 0; j < 16; ++j) {
                const int cc = kq * 16 + j;
                pp += resbuf[cc] * Wo_t[cc * 64 + c_lane];
            }
            ybuf[kq * 64 + c_lane] = pp;
        }
        __syncthreads();

        // ---- phase 6: bias + LayerNorm + relu + store (wave 0) ----
        if (t < 64) {
            const float y = ybuf[t] + ybuf[64 + t] + ybuf[128 + t] + ybuf[192 + t] + pbout;
            float s = y;
            #pragma unroll
            for (int off = 32; off > 0; off >>= 1) s += __shfl_xor(s, off);
            const float mu = s * (1.f / 64.f);
            const float dv = y - mu;
            float v2 = dv * dv;
            #pragma unroll
            for (int off = 32; off > 0; off >>= 1) v2 += __shfl_xor(v2, off);
            const float var = v2 * (1.f / 64.f);
            const float o = plng * dv * rsqrtf(var + EPSF) + plnb;
            out[(size_t)pt * 64 + t] = fmaxf(o, 0.f);
        }
        __syncthreads();
    }
}

extern "C" void kernel_launch(void* const* d_in, const int* in_sizes, int n_in,
                              void* d_out, int out_size, void* d_ws, size_t ws_size,
                              hipStream_t stream) {
    hipLaunchKernelGGL(bridgenet_kernel, dim3(NBLOCK), dim3(256), 0, stream,
        (const float*)d_in[0],  (const float*)d_in[1],  (const int*)d_in[2],
        (const float*)d_in[3],  (const float*)d_in[4],
        (const float*)d_in[5],  (const float*)d_in[6],  (const float*)d_in[7],  (const float*)d_in[8],
        (const float*)d_in[9],  (const float*)d_in[10],
        (const float*)d_in[11], (const float*)d_in[12], (const float*)d_in[13], (const float*)d_in[14],
        (const float*)d_in[15], (const float*)d_in[16],
        (const float*)d_in[17], (const float*)d_in[18],
        (const float*)d_in[19], (const float*)d_in[20],
        (float*)d_out);
}

// Round 2
// 250.069 us; speedup vs baseline: 1.5444x; 1.5444x over previous
//
#include <hip/hip_runtime.h>
#include <hip/hip_bf16.h>

#define EPSF 1e-5f

typedef __attribute__((ext_vector_type(8))) short bf16x8;
typedef __attribute__((ext_vector_type(4))) float f32x4;

constexpr int B_ = 2, N_ = 16384;
constexpr int HSTR = 72;   // hbuf row stride in bf16 elems (144B: 16B-aligned, 2-way banks)
constexpr int RSTR = 72;   // resstage row stride

__device__ __forceinline__ short f2bf(float f) {
    __hip_bfloat16 h = __float2bfloat16(f);
    short s;
    __builtin_memcpy(&s, &h, 2);
    return s;
}

__global__ __launch_bounds__(256) void bridgenet_mfma(
    const float* __restrict__ points,
    const float* __restrict__ features,
    const int*   __restrict__ gidx,
    const float* __restrict__ Wpos,
    const float* __restrict__ bposv,
    const float* __restrict__ bn1g, const float* __restrict__ bn1b,
    const float* __restrict__ bn1m, const float* __restrict__ bn1v,
    const float* __restrict__ Wgcm,
    const float* __restrict__ bgcm,
    const float* __restrict__ bn2g, const float* __restrict__ bn2b,
    const float* __restrict__ bn2m, const float* __restrict__ bn2v,
    const float* __restrict__ Watt,
    const float* __restrict__ batt,
    const float* __restrict__ Wout,
    const float* __restrict__ bout,
    const float* __restrict__ lng, const float* __restrict__ lnb,
    float* __restrict__ out)
{
    __shared__ __align__(16) short hbuf[4][32 * HSTR];   // per-wave h tiles, bf16 [k][c]
    __shared__ __align__(16) short resstage[16 * RSTR];  // res rows for phase D, bf16 [ptl][c]

    const int t    = threadIdx.x;
    const int w    = t >> 6;      // wave 0..3
    const int l    = t & 63;
    const int l15  = l & 15;
    const int quad = l >> 4;

    // ---------- constant fragments (registers) ----------
    // pos-MLP B-frag: B[g][c] = Wpos[c][g], g padded 10->32
    bf16x8 bposf[4];
    #pragma unroll
    for (int nt = 0; nt < 4; ++nt) {
        const int c = nt * 16 + l15;
        #pragma unroll
        for (int j = 0; j < 8; ++j) {
            const int g = quad * 8 + j;
            bposf[nt][j] = f2bf(g < 10 ? Wpos[c * 10 + g] : 0.f);
        }
    }
    // GCM B-frag: B[c][d] = Wgcm[d*64 + c]
    bf16x8 b2f[4][2];
    #pragma unroll
    for (int nt = 0; nt < 4; ++nt)
        #pragma unroll
        for (int ks = 0; ks < 2; ++ks) {
            const int d = nt * 16 + l15;
            #pragma unroll
            for (int j = 0; j < 8; ++j)
                b2f[nt][ks][j] = f2bf(Wgcm[d * 64 + ks * 32 + quad * 8 + j]);
        }
    // folded BN params per channel c = nt*16 + l15
    float ps1f[4], pb1f[4], ps2f[4], pb2f[4];
    #pragma unroll
    for (int nt = 0; nt < 4; ++nt) {
        const int c = nt * 16 + l15;
        ps1f[nt] = bn1g[c] * rsqrtf(bn1v[c] + EPSF);
        pb1f[nt] = ps1f[nt] * (bposv[c] - bn1m[c]) + bn1b[c];
        ps2f[nt] = bn2g[c] * rsqrtf(bn2v[c] + EPSF);
        pb2f[nt] = ps2f[nt] * (bgcm[c] - bn2m[c]) + bn2b[c];
    }
    // attention weights for this lane's C-frag rows k = mt*16 + quad*4 + r
    float wat[2][4];
    #pragma unroll
    for (int mt = 0; mt < 2; ++mt)
        #pragma unroll
        for (int r = 0; r < 4; ++r)
            wat[mt][r] = Watt[mt * 16 + quad * 4 + r];
    const float battv = batt[0];

    const f32x4 zero4 = {0.f, 0.f, 0.f, 0.f};
    short* hb = hbuf[w];

    // ---------- main loop: 1 wave = 1 point, no block barriers ----------
    for (int i = 0; i < 4; ++i) {
        const int pt = blockIdx.x * 16 + w * 4 + i;
        const int bb = (pt >> 14) * N_;                  // b * N
        const float xi0 = points[(size_t)pt * 3 + 0];
        const float xi1 = points[(size_t)pt * 3 + 1];
        const float xi2 = points[(size_t)pt * 3 + 2];

        // --- geo A-frags, built in registers (k = mt*16 + l15, g = quad*8+j) ---
        bf16x8 ageo[2];
        #pragma unroll
        for (int mt = 0; mt < 2; ++mt) {
            const int gi = gidx[(size_t)pt * 32 + mt * 16 + l15];
            const float* pp = points + (size_t)(bb + gi) * 3;
            const float px = pp[0], py = pp[1], pz = pp[2];
            const float dx = xi0 - px, dy = xi1 - py, dz = xi2 - pz;
            const float dist = sqrtf(dx * dx + dy * dy + dz * dz);
            bf16x8 fr = {0, 0, 0, 0, 0, 0, 0, 0};
            if (quad == 0) {
                fr[0] = f2bf(xi0); fr[1] = f2bf(xi1); fr[2] = f2bf(xi2);
                fr[3] = f2bf(px);  fr[4] = f2bf(py);  fr[5] = f2bf(pz);
                fr[6] = f2bf(dx);  fr[7] = f2bf(dy);
            } else if (quad == 1) {
                fr[0] = f2bf(dz);  fr[1] = f2bf(dist);
            }
            ageo[mt] = fr;
        }

        // --- pos-MLP MFMA: out[k][c] = sum_g geo[k][g] * Wpos[c][g] ---
        f32x4 acc1[2][4];
        #pragma unroll
        for (int mt = 0; mt < 2; ++mt)
            #pragma unroll
            for (int nt = 0; nt < 4; ++nt)
                acc1[mt][nt] = __builtin_amdgcn_mfma_f32_16x16x32_bf16(
                    ageo[mt], bposf[nt], zero4, 0, 0, 0);

        // --- epilogue 1: bn1+relu + gathered-feature add, h -> LDS (bf16) ---
        #pragma unroll
        for (int mt = 0; mt < 2; ++mt) {
            #pragma unroll
            for (int r = 0; r < 4; ++r) {
                const int k = mt * 16 + quad * 4 + r;
                const int gi = gidx[(size_t)pt * 32 + k];
                const float* frow = features + (size_t)(bb + gi) * 64;
                #pragma unroll
                for (int nt = 0; nt < 4; ++nt) {
                    const int c = nt * 16 + l15;
                    const float e = fmaxf(ps1f[nt] * acc1[mt][nt][r] + pb1f[nt], 0.f);
                    hb[k * HSTR + c] = f2bf(frow[c] + e);
                }
            }
        }

        // --- GCM: A-frags from LDS, 16 MFMAs ---
        bf16x8 a2[2][2];
        #pragma unroll
        for (int mt = 0; mt < 2; ++mt)
            #pragma unroll
            for (int ks = 0; ks < 2; ++ks)
                a2[mt][ks] = *(const bf16x8*)&hb[(mt * 16 + l15) * HSTR + ks * 32 + quad * 8];
        f32x4 acc2[2][4];
        #pragma unroll
        for (int mt = 0; mt < 2; ++mt)
            #pragma unroll
            for (int nt = 0; nt < 4; ++nt) {
                f32x4 a = __builtin_amdgcn_mfma_f32_16x16x32_bf16(a2[mt][0], b2f[nt][0], zero4, 0, 0, 0);
                acc2[mt][nt] = __builtin_amdgcn_mfma_f32_16x16x32_bf16(a2[mt][1], b2f[nt][1], a, 0, 0, 0);
            }

        // --- epilogue 2: bn2+relu, attention (softmax over d), pool, residual ---
        float res[4];
        {
            float sp[4], mk[4];
            #pragma unroll
            for (int nt = 0; nt < 4; ++nt) {
                sp[nt] = 0.f; mk[nt] = 0.f;
                #pragma unroll
                for (int mt = 0; mt < 2; ++mt)
                    #pragma unroll
                    for (int r = 0; r < 4; ++r) {
                        const float h2 = fmaxf(ps2f[nt] * acc2[mt][nt][r] + pb2f[nt], 0.f);
                        sp[nt] += h2 * wat[mt][r];
                        mk[nt] = fmaxf(mk[nt], h2);
                    }
                sp[nt] += __shfl_xor(sp[nt], 16);
                sp[nt] += __shfl_xor(sp[nt], 32);
                mk[nt] = fmaxf(mk[nt], __shfl_xor(mk[nt], 16));
                mk[nt] = fmaxf(mk[nt], __shfl_xor(mk[nt], 32));
                sp[nt] += battv;
            }
            float mx = fmaxf(fmaxf(sp[0], sp[1]), fmaxf(sp[2], sp[3]));
            #pragma unroll
            for (int o = 1; o < 16; o <<= 1) mx = fmaxf(mx, __shfl_xor(mx, o));
            float e[4], s = 0.f;
            #pragma unroll
            for (int nt = 0; nt < 4; ++nt) { e[nt] = __expf(sp[nt] - mx); s += e[nt]; }
            #pragma unroll
            for (int o = 1; o < 16; o <<= 1) s += __shfl_xor(s, o);
            const float inv = 1.f / s;
            #pragma unroll
            for (int nt = 0; nt < 4; ++nt)
                res[nt] = e[nt] * inv * mk[nt] + features[(size_t)pt * 64 + nt * 16 + l15];
        }
        // stage res row (values replicated across quads; quad0 writes)
        if (quad == 0) {
            const int ptl = w * 4 + i;
            #pragma unroll
            for (int nt = 0; nt < 4; ++nt)
                resstage[ptl * RSTR + nt * 16 + l15] = f2bf(res[nt]);
        }
    }

    __syncthreads();

    // ---------- phase D: batched out-matmul (16 pts) + LayerNorm + relu ----------
    bf16x8 b3f[4][2];
    #pragma unroll
    for (int nt = 0; nt < 4; ++nt)
        #pragma unroll
        for (int ks = 0; ks < 2; ++ks) {
            const int o = nt * 16 + l15;
            #pragma unroll
            for (int j = 0; j < 8; ++j)
                b3f[nt][ks][j] = f2bf(Wout[o * 64 + ks * 32 + quad * 8 + j]);
        }
    float lngv[4], lnbv[4], boutv[4];
    #pragma unroll
    for (int nt = 0; nt < 4; ++nt) {
        const int o = nt * 16 + l15;
        lngv[nt] = lng[o]; lnbv[nt] = lnb[o]; boutv[nt] = bout[o];
    }
    bf16x8 a3[2];
    #pragma unroll
    for (int ks = 0; ks < 2; ++ks)
        a3[ks] = *(const bf16x8*)&resstage[l15 * RSTR + ks * 32 + quad * 8];
    f32x4 acc3[4];
    #pragma unroll
    for (int nt = 0; nt < 4; ++nt) {
        f32x4 a = __builtin_amdgcn_mfma_f32_16x16x32_bf16(a3[0], b3f[nt][0], zero4, 0, 0, 0);
        acc3[nt] = __builtin_amdgcn_mfma_f32_16x16x32_bf16(a3[1], b3f[nt][1], a, 0, 0, 0);
    }
    // each wave keeps C-frag reg index == w -> row = quad*4 + w (disjoint across waves)
    float y[4], s = 0.f;
    #pragma unroll
    for (int nt = 0; nt < 4; ++nt) { y[nt] = acc3[nt][w] + boutv[nt]; s += y[nt]; }
    #pragma unroll
    for (int o = 1; o < 16; o <<= 1) s += __shfl_xor(s, o);
    const float mu = s * (1.f / 64.f);
    float dv[4], v2 = 0.f;
    #pragma unroll
    for (int nt = 0; nt < 4; ++nt) { dv[nt] = y[nt] - mu; v2 += dv[nt] * dv[nt]; }
    #pragma unroll
    for (int o = 1; o < 16; o <<= 1) v2 += __shfl_xor(v2, o);
    const float rs = rsqrtf(v2 * (1.f / 64.f) + EPSF);
    const int pto = blockIdx.x * 16 + quad * 4 + w;
    #pragma unroll
    for (int nt = 0; nt < 4; ++nt) {
        const float o_ = fmaxf(lngv[nt] * dv[nt] * rs + lnbv[nt], 0.f);
        out[(size_t)pto * 64 + nt * 16 + l15] = o_;
    }
}

extern "C" void kernel_launch(void* const* d_in, const int* in_sizes, int n_in,
                              void* d_out, int out_size, void* d_ws, size_t ws_size,
                              hipStream_t stream) {
    hipLaunchKernelGGL(bridgenet_mfma, dim3((B_ * N_) / 16), dim3(256), 0, stream,
        (const float*)d_in[0],  (const float*)d_in[1],  (const int*)d_in[2],
        (const float*)d_in[3],  (const float*)d_in[4],
        (const float*)d_in[5],  (const float*)d_in[6],  (const float*)d_in[7],  (const float*)d_in[8],
        (const float*)d_in[9],  (const float*)d_in[10],
        (const float*)d_in[11], (const float*)d_in[12], (const float*)d_in[13], (const float*)d_in[14],
        (const float*)d_in[15], (const float*)d_in[16],
        (const float*)d_in[17], (const float*)d_in[18],
        (const float*)d_in[19], (const float*)d_in[20],
        (float*)d_out);
}

// Round 3
// 192.672 us; speedup vs baseline: 2.0045x; 1.2979x over previous
//
#include <hip/hip_runtime.h>
#include <hip/hip_bf16.h>

#define EPSF 1e-5f

typedef __attribute__((ext_vector_type(8))) short bf16x8;
typedef __attribute__((ext_vector_type(4))) short bf16x4;
typedef __attribute__((ext_vector_type(4))) float f32x4;

constexpr int B_ = 2, N_ = 16384;
constexpr int HSTR = 72;   // hbuf row stride in bf16 elems
constexpr int RSTR = 72;   // resstage row stride

__device__ __forceinline__ short f2bf(float f) {
    __hip_bfloat16 h = __float2bfloat16(f);
    short s;
    __builtin_memcpy(&s, &h, 2);
    return s;
}

// Channel interleave: for all 64-wide channel dims, MFMA tile nt / column n
// maps to channel c = n*4 + nt, so one lane's 4 tiles cover 4 CONSECUTIVE
// channels l15*4..+3 -> float4 gathers, b64 LDS writes, float4 stores.
__global__ __launch_bounds__(256) void bridgenet_mfma3(
    const float* __restrict__ points,
    const float* __restrict__ features,
    const int*   __restrict__ gidx,
    const float* __restrict__ Wpos,
    const float* __restrict__ bposv,
    const float* __restrict__ bn1g, const float* __restrict__ bn1b,
    const float* __restrict__ bn1m, const float* __restrict__ bn1v,
    const float* __restrict__ Wgcm,
    const float* __restrict__ bgcm,
    const float* __restrict__ bn2g, const float* __restrict__ bn2b,
    const float* __restrict__ bn2m, const float* __restrict__ bn2v,
    const float* __restrict__ Watt,
    const float* __restrict__ batt,
    const float* __restrict__ Wout,
    const float* __restrict__ bout,
    const float* __restrict__ lng, const float* __restrict__ lnb,
    float* __restrict__ out)
{
    __shared__ __align__(16) short hbuf[4][32 * HSTR];   // per-wave h tiles, bf16 [k][c]
    __shared__ __align__(16) short resstage[16 * RSTR];  // res rows, bf16 [ptl][c]

    const int t    = threadIdx.x;
    const int w    = t >> 6;
    const int l    = t & 63;
    const int l15  = l & 15;
    const int quad = l >> 4;
    const int c4   = l15 * 4;     // this lane's base channel

    // ---------- constant fragments (registers), interleaved channel map ----------
    bf16x8 bposf[4];
    #pragma unroll
    for (int nt = 0; nt < 4; ++nt) {
        const int c = c4 + nt;
        #pragma unroll
        for (int j = 0; j < 8; ++j) {
            const int g = quad * 8 + j;
            bposf[nt][j] = f2bf(g < 10 ? Wpos[c * 10 + g] : 0.f);
        }
    }
    bf16x8 b2f[4][2];
    #pragma unroll
    for (int nt = 0; nt < 4; ++nt)
        #pragma unroll
        for (int ks = 0; ks < 2; ++ks) {
            const int d = c4 + nt;
            #pragma unroll
            for (int j = 0; j < 8; ++j)
                b2f[nt][ks][j] = f2bf(Wgcm[d * 64 + ks * 32 + quad * 8 + j]);
        }

    // folded BN params for channels c4..c4+3 (float4 loads)
    f32x4 ps1, pb1, ps2, pb2;
    {
        const f32x4 g1 = *(const f32x4*)(bn1g + c4);
        const f32x4 b1 = *(const f32x4*)(bn1b + c4);
        const f32x4 m1 = *(const f32x4*)(bn1m + c4);
        const f32x4 v1 = *(const f32x4*)(bn1v + c4);
        const f32x4 bp = *(const f32x4*)(bposv + c4);
        const f32x4 g2 = *(const f32x4*)(bn2g + c4);
        const f32x4 b2 = *(const f32x4*)(bn2b + c4);
        const f32x4 m2 = *(const f32x4*)(bn2m + c4);
        const f32x4 v2 = *(const f32x4*)(bn2v + c4);
        const f32x4 bg = *(const f32x4*)(bgcm + c4);
        #pragma unroll
        for (int j = 0; j < 4; ++j) {
            ps1[j] = g1[j] * rsqrtf(v1[j] + EPSF);
            pb1[j] = ps1[j] * (bp[j] - m1[j]) + b1[j];
            ps2[j] = g2[j] * rsqrtf(v2[j] + EPSF);
            pb2[j] = ps2[j] * (bg[j] - m2[j]) + b2[j];
        }
    }
    float wat[2][4];
    #pragma unroll
    for (int mt = 0; mt < 2; ++mt)
        #pragma unroll
        for (int r = 0; r < 4; ++r)
            wat[mt][r] = Watt[mt * 16 + quad * 4 + r];
    const float battv = batt[0];

    const f32x4 zero4 = {0.f, 0.f, 0.f, 0.f};
    short* hb = hbuf[w];

    // ---------- main loop: 1 wave = 1 point, no block barriers ----------
    for (int i = 0; i < 4; ++i) {
        const int pt = blockIdx.x * 16 + w * 4 + i;
        const int bb = (pt >> 14) * N_;

        // --- early loads: indices, residual, neighbor coords, feature rows ---
        int giv[2];
        giv[0] = gidx[(size_t)pt * 32 + l15];
        giv[1] = gidx[(size_t)pt * 32 + 16 + l15];
        const f32x4 resid = *(const f32x4*)(features + (size_t)pt * 64 + c4);
        const float xi0 = points[(size_t)pt * 3 + 0];
        const float xi1 = points[(size_t)pt * 3 + 1];
        const float xi2 = points[(size_t)pt * 3 + 2];
        float px[2], py[2], pz[2];
        #pragma unroll
        for (int mt = 0; mt < 2; ++mt) {
            const float* pp = points + (size_t)(bb + giv[mt]) * 3;
            px[mt] = pp[0]; py[mt] = pp[1]; pz[mt] = pp[2];
        }
        f32x4 f4[2][4];   // gathered feature rows, issued before MFMA1
        #pragma unroll
        for (int mt = 0; mt < 2; ++mt)
            #pragma unroll
            for (int r = 0; r < 4; ++r) {
                const int gs = __shfl(giv[mt], quad * 4 + r);
                f4[mt][r] = *(const f32x4*)(features + (size_t)(bb + gs) * 64 + c4);
            }

        // --- geo A-frags in registers (k = mt*16 + l15, g = quad*8+j) ---
        bf16x8 ageo[2];
        #pragma unroll
        for (int mt = 0; mt < 2; ++mt) {
            const float dx = xi0 - px[mt], dy = xi1 - py[mt], dz = xi2 - pz[mt];
            const float dist = sqrtf(dx * dx + dy * dy + dz * dz);
            bf16x8 fr = {0, 0, 0, 0, 0, 0, 0, 0};
            if (quad == 0) {
                fr[0] = f2bf(xi0);    fr[1] = f2bf(xi1); fr[2] = f2bf(xi2);
                fr[3] = f2bf(px[mt]); fr[4] = f2bf(py[mt]); fr[5] = f2bf(pz[mt]);
                fr[6] = f2bf(dx);     fr[7] = f2bf(dy);
            } else if (quad == 1) {
                fr[0] = f2bf(dz);     fr[1] = f2bf(dist);
            }
            ageo[mt] = fr;
        }

        // --- pos-MLP MFMA ---
        f32x4 acc1[2][4];
        #pragma unroll
        for (int mt = 0; mt < 2; ++mt)
            #pragma unroll
            for (int nt = 0; nt < 4; ++nt)
                acc1[mt][nt] = __builtin_amdgcn_mfma_f32_16x16x32_bf16(
                    ageo[mt], bposf[nt], zero4, 0, 0, 0);

        // --- epilogue 1: bn1+relu + feature add, packed b64 writes ---
        #pragma unroll
        for (int mt = 0; mt < 2; ++mt)
            #pragma unroll
            for (int r = 0; r < 4; ++r) {
                const int k = mt * 16 + quad * 4 + r;
                bf16x4 hv;
                #pragma unroll
                for (int j = 0; j < 4; ++j) {
                    const float e = fmaxf(ps1[j] * acc1[mt][j][r] + pb1[j], 0.f);
                    hv[j] = f2bf(f4[mt][r][j] + e);
                }
                *(bf16x4*)&hb[k * HSTR + c4] = hv;
            }

        // --- GCM: A-frags from LDS, 16 MFMAs ---
        bf16x8 a2[2][2];
        #pragma unroll
        for (int mt = 0; mt < 2; ++mt)
            #pragma unroll
            for (int ks = 0; ks < 2; ++ks)
                a2[mt][ks] = *(const bf16x8*)&hb[(mt * 16 + l15) * HSTR + ks * 32 + quad * 8];
        f32x4 acc2[2][4];
        #pragma unroll
        for (int mt = 0; mt < 2; ++mt)
            #pragma unroll
            for (int nt = 0; nt < 4; ++nt) {
                f32x4 a = __builtin_amdgcn_mfma_f32_16x16x32_bf16(a2[mt][0], b2f[nt][0], zero4, 0, 0, 0);
                acc2[mt][nt] = __builtin_amdgcn_mfma_f32_16x16x32_bf16(a2[mt][1], b2f[nt][1], a, 0, 0, 0);
            }

        // --- epilogue 2: bn2+relu, attention softmax over d, pool, residual ---
        float res[4];
        {
            float sp[4], mk[4];
            #pragma unroll
            for (int nt = 0; nt < 4; ++nt) {
                sp[nt] = 0.f; mk[nt] = 0.f;
                #pragma unroll
                for (int mt = 0; mt < 2; ++mt)
                    #pragma unroll
                    for (int r = 0; r < 4; ++r) {
                        const float h2 = fmaxf(ps2[nt] * acc2[mt][nt][r] + pb2[nt], 0.f);
                        sp[nt] += h2 * wat[mt][r];
                        mk[nt] = fmaxf(mk[nt], h2);
                    }
                sp[nt] += __shfl_xor(sp[nt], 16);
                sp[nt] += __shfl_xor(sp[nt], 32);
                mk[nt] = fmaxf(mk[nt], __shfl_xor(mk[nt], 16));
                mk[nt] = fmaxf(mk[nt], __shfl_xor(mk[nt], 32));
                sp[nt] += battv;
            }
            float mx = fmaxf(fmaxf(sp[0], sp[1]), fmaxf(sp[2], sp[3]));
            #pragma unroll
            for (int o = 1; o < 16; o <<= 1) mx = fmaxf(mx, __shfl_xor(mx, o));
            float e[4], s = 0.f;
            #pragma unroll
            for (int nt = 0; nt < 4; ++nt) { e[nt] = __expf(sp[nt] - mx); s += e[nt]; }
            #pragma unroll
            for (int o = 1; o < 16; o <<= 1) s += __shfl_xor(s, o);
            const float inv = 1.f / s;
            #pragma unroll
            for (int nt = 0; nt < 4; ++nt)
                res[nt] = e[nt] * inv * mk[nt] + resid[nt];
        }
        if (quad == 0) {
            const int ptl = w * 4 + i;
            bf16x4 rv;
            #pragma unroll
            for (int j = 0; j < 4; ++j) rv[j] = f2bf(res[j]);
            *(bf16x4*)&resstage[ptl * RSTR + c4] = rv;
        }
    }

    __syncthreads();

    // ---------- phase D: batched out-matmul (16 pts) + LayerNorm + relu ----------
    bf16x8 b3f[4][2];
    #pragma unroll
    for (int nt = 0; nt < 4; ++nt)
        #pragma unroll
        for (int ks = 0; ks < 2; ++ks) {
            const int o = c4 + nt;
            #pragma unroll
            for (int j = 0; j < 8; ++j)
                b3f[nt][ks][j] = f2bf(Wout[o * 64 + ks * 32 + quad * 8 + j]);
        }
    const f32x4 lngv  = *(const f32x4*)(lng + c4);
    const f32x4 lnbv  = *(const f32x4*)(lnb + c4);
    const f32x4 boutv = *(const f32x4*)(bout + c4);

    bf16x8 a3[2];
    #pragma unroll
    for (int ks = 0; ks < 2; ++ks)
        a3[ks] = *(const bf16x8*)&resstage[l15 * RSTR + ks * 32 + quad * 8];
    f32x4 acc3[4];
    #pragma unroll
    for (int nt = 0; nt < 4; ++nt) {
        f32x4 a = __builtin_amdgcn_mfma_f32_16x16x32_bf16(a3[0], b3f[nt][0], zero4, 0, 0, 0);
        acc3[nt] = __builtin_amdgcn_mfma_f32_16x16x32_bf16(a3[1], b3f[nt][1], a, 0, 0, 0);
    }
    // each wave keeps C-frag reg index == w -> point row = quad*4 + w
    float y[4], s = 0.f;
    #pragma unroll
    for (int nt = 0; nt < 4; ++nt) { y[nt] = acc3[nt][w] + boutv[nt]; s += y[nt]; }
    #pragma unroll
    for (int o = 1; o < 16; o <<= 1) s += __shfl_xor(s, o);
    const float mu = s * (1.f / 64.f);
    float dv[4], v2 = 0.f;
    #pragma unroll
    for (int nt = 0; nt < 4; ++nt) { dv[nt] = y[nt] - mu; v2 += dv[nt] * dv[nt]; }
    #pragma unroll
    for (int o = 1; o < 16; o <<= 1) v2 += __shfl_xor(v2, o);
    const float rs = rsqrtf(v2 * (1.f / 64.f) + EPSF);
    const int pto = blockIdx.x * 16 + quad * 4 + w;
    f32x4 ov;
    #pragma unroll
    for (int nt = 0; nt < 4; ++nt)
        ov[nt] = fmaxf(lngv[nt] * dv[nt] * rs + lnbv[nt], 0.f);
    *(f32x4*)(out + (size_t)pto * 64 + c4) = ov;
}

extern "C" void kernel_launch(void* const* d_in, const int* in_sizes, int n_in,
                              void* d_out, int out_size, void* d_ws, size_t ws_size,
                              hipStream_t stream) {
    hipLaunchKernelGGL(bridgenet_mfma3, dim3((B_ * N_) / 16), dim3(256), 0, stream,
        (const float*)d_in[0],  (const float*)d_in[1],  (const int*)d_in[2],
        (const float*)d_in[3],  (const float*)d_in[4],
        (const float*)d_in[5],  (const float*)d_in[6],  (const float*)d_in[7],  (const float*)d_in[8],
        (const float*)d_in[9],  (const float*)d_in[10],
        (const float*)d_in[11], (const float*)d_in[12], (const float*)d_in[13], (const float*)d_in[14],
        (const float*)d_in[15], (const float*)d_in[16],
        (const float*)d_in[17], (const float*)d_in[18],
        (const float*)d_in[19], (const float*)d_in[20],
        (float*)d_out);
}

// Round 4
// 191.740 us; speedup vs baseline: 2.0143x; 1.0049x over previous
//
#include <hip/hip_runtime.h>
#include <hip/hip_bf16.h>

#define EPSF 1e-5f

typedef __attribute__((ext_vector_type(8))) short bf16x8;
typedef __attribute__((ext_vector_type(4))) short bf16x4;
typedef __attribute__((ext_vector_type(4))) float f32x4;

constexpr int B_ = 2, N_ = 16384;
constexpr int HSTR = 72;   // hbuf row stride in bf16 elems
constexpr int RSTR = 72;   // resstage row stride
constexpr int PPW  = 8;    // points per wave (pipelined)
constexpr int PPB  = 32;   // points per block

__device__ __forceinline__ short f2bf(float f) {
    __hip_bfloat16 h = __float2bfloat16(f);
    short s;
    __builtin_memcpy(&s, &h, 2);
    return s;
}

// Channel interleave: MFMA tile nt / column n maps to channel c = n*4 + nt,
// so one lane's 4 tiles cover channels l15*4..+3 -> float4 gathers, b64 LDS
// writes, float4 stores. Scattered loads are software-pipelined: gidx 2 pts
// ahead, dependent gathers 1 pt ahead, so compute never waits on fresh VMEM.
__global__ __launch_bounds__(256) void bridgenet_mfma4(
    const float* __restrict__ points,
    const float* __restrict__ features,
    const int*   __restrict__ gidx,
    const float* __restrict__ Wpos,
    const float* __restrict__ bposv,
    const float* __restrict__ bn1g, const float* __restrict__ bn1b,
    const float* __restrict__ bn1m, const float* __restrict__ bn1v,
    const float* __restrict__ Wgcm,
    const float* __restrict__ bgcm,
    const float* __restrict__ bn2g, const float* __restrict__ bn2b,
    const float* __restrict__ bn2m, const float* __restrict__ bn2v,
    const float* __restrict__ Watt,
    const float* __restrict__ batt,
    const float* __restrict__ Wout,
    const float* __restrict__ bout,
    const float* __restrict__ lng, const float* __restrict__ lnb,
    float* __restrict__ out)
{
    __shared__ __align__(16) short hbuf[4][32 * HSTR];
    __shared__ __align__(16) short resstage[PPB * RSTR];

    const int t    = threadIdx.x;
    const int w    = t >> 6;
    const int l    = t & 63;
    const int l15  = l & 15;
    const int quad = l >> 4;
    const int c4   = l15 * 4;

    // ---------- constant fragments ----------
    bf16x8 bposf[4];
    #pragma unroll
    for (int nt = 0; nt < 4; ++nt) {
        const int c = c4 + nt;
        #pragma unroll
        for (int j = 0; j < 8; ++j) {
            const int g = quad * 8 + j;
            bposf[nt][j] = f2bf(g < 10 ? Wpos[c * 10 + g] : 0.f);
        }
    }
    bf16x8 b2f[4][2];
    #pragma unroll
    for (int nt = 0; nt < 4; ++nt)
        #pragma unroll
        for (int ks = 0; ks < 2; ++ks) {
            const int d = c4 + nt;
            #pragma unroll
            for (int j = 0; j < 8; ++j)
                b2f[nt][ks][j] = f2bf(Wgcm[d * 64 + ks * 32 + quad * 8 + j]);
        }
    f32x4 ps1, pb1, ps2, pb2;
    {
        const f32x4 g1 = *(const f32x4*)(bn1g + c4);
        const f32x4 b1 = *(const f32x4*)(bn1b + c4);
        const f32x4 m1 = *(const f32x4*)(bn1m + c4);
        const f32x4 v1 = *(const f32x4*)(bn1v + c4);
        const f32x4 bp = *(const f32x4*)(bposv + c4);
        const f32x4 g2 = *(const f32x4*)(bn2g + c4);
        const f32x4 b2 = *(const f32x4*)(bn2b + c4);
        const f32x4 m2 = *(const f32x4*)(bn2m + c4);
        const f32x4 v2 = *(const f32x4*)(bn2v + c4);
        const f32x4 bg = *(const f32x4*)(bgcm + c4);
        #pragma unroll
        for (int j = 0; j < 4; ++j) {
            ps1[j] = g1[j] * rsqrtf(v1[j] + EPSF);
            pb1[j] = ps1[j] * (bp[j] - m1[j]) + b1[j];
            ps2[j] = g2[j] * rsqrtf(v2[j] + EPSF);
            pb2[j] = ps2[j] * (bg[j] - m2[j]) + b2[j];
        }
    }
    float wat[2][4];
    #pragma unroll
    for (int mt = 0; mt < 2; ++mt)
        #pragma unroll
        for (int r = 0; r < 4; ++r)
            wat[mt][r] = Watt[mt * 16 + quad * 4 + r];
    const float battv = batt[0];

    const f32x4 zero4 = {0.f, 0.f, 0.f, 0.f};
    short* hb = hbuf[w];

    const int bb   = (int)((blockIdx.x * PPB) >> 14) * N_;   // block-uniform batch base
    const int base = blockIdx.x * PPB + w * PPW;

    // ---------- pipeline state (full unroll -> registers) ----------
    int   giv[PPW][2];
    float xi[PPW][3];
    float px[PPW][2], py[PPW][2], pz[PPW][2];
    f32x4 f4[PPW][2][4];
    f32x4 resid[PPW];

    auto loadIdx = [&](int i) {
        const int pt = base + i;
        giv[i][0] = gidx[(size_t)pt * 32 + l15];
        giv[i][1] = gidx[(size_t)pt * 32 + 16 + l15];
    };
    auto loadGather = [&](int i) {
        const int pt = base + i;
        xi[i][0] = points[(size_t)pt * 3 + 0];
        xi[i][1] = points[(size_t)pt * 3 + 1];
        xi[i][2] = points[(size_t)pt * 3 + 2];
        resid[i] = *(const f32x4*)(features + (size_t)pt * 64 + c4);
        #pragma unroll
        for (int mt = 0; mt < 2; ++mt) {
            const float* pp = points + (size_t)(bb + giv[i][mt]) * 3;
            px[i][mt] = pp[0]; py[i][mt] = pp[1]; pz[i][mt] = pp[2];
        }
        #pragma unroll
        for (int mt = 0; mt < 2; ++mt)
            #pragma unroll
            for (int r = 0; r < 4; ++r) {
                const int gs = __shfl(giv[i][mt], quad * 4 + r);
                f4[i][mt][r] = *(const f32x4*)(features + (size_t)(bb + gs) * 64 + c4);
            }
    };

    // prologue
    loadIdx(0);
    loadIdx(1);
    loadGather(0);

    #pragma unroll
    for (int i = 0; i < PPW; ++i) {
        if (i + 2 < PPW) loadIdx(i + 2);
        if (i + 1 < PPW) loadGather(i + 1);

        // --- geo A-frags (k = mt*16 + l15, g = quad*8+j) ---
        bf16x8 ageo[2];
        #pragma unroll
        for (int mt = 0; mt < 2; ++mt) {
            const float dx = xi[i][0] - px[i][mt];
            const float dy = xi[i][1] - py[i][mt];
            const float dz = xi[i][2] - pz[i][mt];
            const float dist = sqrtf(dx * dx + dy * dy + dz * dz);
            bf16x8 fr = {0, 0, 0, 0, 0, 0, 0, 0};
            if (quad == 0) {
                fr[0] = f2bf(xi[i][0]); fr[1] = f2bf(xi[i][1]); fr[2] = f2bf(xi[i][2]);
                fr[3] = f2bf(px[i][mt]); fr[4] = f2bf(py[i][mt]); fr[5] = f2bf(pz[i][mt]);
                fr[6] = f2bf(dx);        fr[7] = f2bf(dy);
            } else if (quad == 1) {
                fr[0] = f2bf(dz);        fr[1] = f2bf(dist);
            }
            ageo[mt] = fr;
        }

        // --- pos-MLP MFMA ---
        f32x4 acc1[2][4];
        #pragma unroll
        for (int mt = 0; mt < 2; ++mt)
            #pragma unroll
            for (int nt = 0; nt < 4; ++nt)
                acc1[mt][nt] = __builtin_amdgcn_mfma_f32_16x16x32_bf16(
                    ageo[mt], bposf[nt], zero4, 0, 0, 0);

        // --- epilogue 1: bn1+relu + feature add, packed b64 writes ---
        #pragma unroll
        for (int mt = 0; mt < 2; ++mt)
            #pragma unroll
            for (int r = 0; r < 4; ++r) {
                const int k = mt * 16 + quad * 4 + r;
                bf16x4 hv;
                #pragma unroll
                for (int j = 0; j < 4; ++j) {
                    const float e = fmaxf(ps1[j] * acc1[mt][j][r] + pb1[j], 0.f);
                    hv[j] = f2bf(f4[i][mt][r][j] + e);
                }
                *(bf16x4*)&hb[k * HSTR + c4] = hv;
            }

        // --- GCM: A-frags from LDS, 16 MFMAs ---
        bf16x8 a2[2][2];
        #pragma unroll
        for (int mt = 0; mt < 2; ++mt)
            #pragma unroll
            for (int ks = 0; ks < 2; ++ks)
                a2[mt][ks] = *(const bf16x8*)&hb[(mt * 16 + l15) * HSTR + ks * 32 + quad * 8];
        f32x4 acc2[2][4];
        #pragma unroll
        for (int mt = 0; mt < 2; ++mt)
            #pragma unroll
            for (int nt = 0; nt < 4; ++nt) {
                f32x4 a = __builtin_amdgcn_mfma_f32_16x16x32_bf16(a2[mt][0], b2f[nt][0], zero4, 0, 0, 0);
                acc2[mt][nt] = __builtin_amdgcn_mfma_f32_16x16x32_bf16(a2[mt][1], b2f[nt][1], a, 0, 0, 0);
            }

        // --- epilogue 2: bn2+relu, attention softmax (no max-sub: scores
        //     bounded ~|30|, exp cannot overflow; softmax is shift-invariant) ---
        float res[4];
        {
            float sp[4], mk[4];
            #pragma unroll
            for (int nt = 0; nt < 4; ++nt) {
                sp[nt] = 0.f; mk[nt] = 0.f;
                #pragma unroll
                for (int mt = 0; mt < 2; ++mt)
                    #pragma unroll
                    for (int r = 0; r < 4; ++r) {
                        const float h2 = fmaxf(ps2[nt] * acc2[mt][nt][r] + pb2[nt], 0.f);
                        sp[nt] += h2 * wat[mt][r];
                        mk[nt] = fmaxf(mk[nt], h2);
                    }
                sp[nt] += __shfl_xor(sp[nt], 16);
                sp[nt] += __shfl_xor(sp[nt], 32);
                mk[nt] = fmaxf(mk[nt], __shfl_xor(mk[nt], 16));
                mk[nt] = fmaxf(mk[nt], __shfl_xor(mk[nt], 32));
            }
            float e[4], s = 0.f;
            #pragma unroll
            for (int nt = 0; nt < 4; ++nt) { e[nt] = __expf(sp[nt] + battv); s += e[nt]; }
            #pragma unroll
            for (int o = 1; o < 16; o <<= 1) s += __shfl_xor(s, o);
            const float inv = 1.f / s;
            #pragma unroll
            for (int nt = 0; nt < 4; ++nt)
                res[nt] = e[nt] * inv * mk[nt] + resid[i][nt];
        }
        if (quad == 0) {
            bf16x4 rv;
            #pragma unroll
            for (int j = 0; j < 4; ++j) rv[j] = f2bf(res[j]);
            *(bf16x4*)&resstage[(w * PPW + i) * RSTR + c4] = rv;
        }
    }

    __syncthreads();

    // ---------- phase D: batched out-matmul (32 pts) + LayerNorm + relu ----------
    bf16x8 b3f[4][2];
    #pragma unroll
    for (int nt = 0; nt < 4; ++nt)
        #pragma unroll
        for (int ks = 0; ks < 2; ++ks) {
            const int o = c4 + nt;
            #pragma unroll
            for (int j = 0; j < 8; ++j)
                b3f[nt][ks][j] = f2bf(Wout[o * 64 + ks * 32 + quad * 8 + j]);
        }
    const f32x4 lngv  = *(const f32x4*)(lng + c4);
    const f32x4 lnbv  = *(const f32x4*)(lnb + c4);
    const f32x4 boutv = *(const f32x4*)(bout + c4);

    #pragma unroll
    for (int mt = 0; mt < 2; ++mt) {
        bf16x8 a3[2];
        #pragma unroll
        for (int ks = 0; ks < 2; ++ks)
            a3[ks] = *(const bf16x8*)&resstage[(mt * 16 + l15) * RSTR + ks * 32 + quad * 8];
        f32x4 acc3[4];
        #pragma unroll
        for (int nt = 0; nt < 4; ++nt) {
            f32x4 a = __builtin_amdgcn_mfma_f32_16x16x32_bf16(a3[0], b3f[nt][0], zero4, 0, 0, 0);
            acc3[nt] = __builtin_amdgcn_mfma_f32_16x16x32_bf16(a3[1], b3f[nt][1], a, 0, 0, 0);
        }
        // wave keeps C-frag reg index == w -> point row = mt*16 + quad*4 + w
        float y[4], s = 0.f;
        #pragma unroll
        for (int nt = 0; nt < 4; ++nt) { y[nt] = acc3[nt][w] + boutv[nt]; s += y[nt]; }
        #pragma unroll
        for (int o = 1; o < 16; o <<= 1) s += __shfl_xor(s, o);
        const float mu = s * (1.f / 64.f);
        float dv[4], v2 = 0.f;
        #pragma unroll
        for (int nt = 0; nt < 4; ++nt) { dv[nt] = y[nt] - mu; v2 += dv[nt] * dv[nt]; }
        #pragma unroll
        for (int o = 1; o < 16; o <<= 1) v2 += __shfl_xor(v2, o);
        const float rs = rsqrtf(v2 * (1.f / 64.f) + EPSF);
        const int pto = blockIdx.x * PPB + mt * 16 + quad * 4 + w;
        f32x4 ov;
        #pragma unroll
        for (int nt = 0; nt < 4; ++nt)
            ov[nt] = fmaxf(lngv[nt] * dv[nt] * rs + lnbv[nt], 0.f);
        *(f32x4*)(out + (size_t)pto * 64 + c4) = ov;
    }
}

extern "C" void kernel_launch(void* const* d_in, const int* in_sizes, int n_in,
                              void* d_out, int out_size, void* d_ws, size_t ws_size,
                              hipStream_t stream) {
    hipLaunchKernelGGL(bridgenet_mfma4, dim3((B_ * N_) / PPB), dim3(256), 0, stream,
        (const float*)d_in[0],  (const float*)d_in[1],  (const int*)d_in[2],
        (const float*)d_in[3],  (const float*)d_in[4],
        (const float*)d_in[5],  (const float*)d_in[6],  (const float*)d_in[7],  (const float*)d_in[8],
        (const float*)d_in[9],  (const float*)d_in[10],
        (const float*)d_in[11], (const float*)d_in[12], (const float*)d_in[13], (const float*)d_in[14],
        (const float*)d_in[15], (const float*)d_in[16],
        (const float*)d_in[17], (const float*)d_in[18],
        (const float*)d_in[19], (const float*)d_in[20],
        (float*)d_out);
}